// Round 1
// baseline (508.915 us; speedup 1.0000x reference)
//
#include <hip/hip_runtime.h>
#include <math.h>

#define BB_ 256
#define NN_ 512
#define SS_ 32
#define NP1 513
#define SP1 33
#define D_ENT 256
#define D_KEY 32
#define D_IN 1024
#define D_FUNC 256
#define D_TYPE 259
#define INV_N (1.0f/512.0f)

__device__ __forceinline__ float sigmoidf_(float x) { return 1.0f / (1.0f + expf(-x)); }

// ---------------------------------------------------------------------------
// K1: pad_key[b,n,k] = sum_d ent[b,n,d]*W_key[k,d] + b_key[k]   (n < 512)
// thread = one entity, 32 accumulators; A staged in LDS, W via scalar loads.
// grid 512 x 256
// ---------------------------------------------------------------------------
__global__ __launch_bounds__(256) void key_kernel(
    const float* __restrict__ ent, const float* __restrict__ Wk,
    const float* __restrict__ bk, float* __restrict__ pad_key)
{
    __shared__ float a_lds[256 * 33];
    const int tid = threadIdx.x;
    const size_t ebase = (size_t)blockIdx.x * 256;

    float acc[32];
#pragma unroll
    for (int k = 0; k < 32; k++) acc[k] = 0.0f;

    for (int ic = 0; ic < 8; ++ic) {
        if (ic) __syncthreads();
        // stage A chunk: entities [0..255], i in [ic*32, ic*32+32)
#pragma unroll
        for (int p = 0; p < 8; p++) {
            int e = p * 32 + (tid >> 3);
            int i4 = tid & 7;
            const float4 v = *(const float4*)(ent + (ebase + e) * 256 + ic * 32 + i4 * 4);
            float* d = &a_lds[e * 33 + i4 * 4];
            d[0] = v.x; d[1] = v.y; d[2] = v.z; d[3] = v.w;
        }
        __syncthreads();
        float a[32];
#pragma unroll
        for (int i = 0; i < 32; i++) a[i] = a_lds[tid * 33 + i];
#pragma unroll
        for (int k = 0; k < 32; k++) {
            const float* wr = Wk + k * 256 + ic * 32;   // uniform -> s_load
#pragma unroll
            for (int i = 0; i < 32; i++) acc[k] = fmaf(a[i], wr[i], acc[k]);
        }
    }
    const size_t g = ebase + tid;
    const size_t b = g >> 9, n = g & 511;
    float* out = pad_key + (b * NP1 + n) * 32;
#pragma unroll
    for (int k = 0; k < 32; k++) acc[k] += bk[k];
#pragma unroll
    for (int k4 = 0; k4 < 8; k4++) {
        float4 v = make_float4(acc[k4*4], acc[k4*4+1], acc[k4*4+2], acc[k4*4+3]);
        *(float4*)(out + k4 * 4) = v;
    }
}

// ---------------------------------------------------------------------------
// K2: func_embed = relu(atm @ W_func^T + b_func); also write end rows of pad_key
// grid 256 x 256
// ---------------------------------------------------------------------------
__global__ __launch_bounds__(256) void func_end_kernel(
    const float* __restrict__ atm, const float* __restrict__ Wf,
    const float* __restrict__ bf, const float* __restrict__ endv,
    float* __restrict__ func_embed, float* __restrict__ pad_key)
{
    __shared__ float a_lds[D_TYPE];
    const int b = blockIdx.x, tid = threadIdx.x;
    a_lds[tid] = atm[(size_t)b * D_TYPE + tid];
    if (tid < 3) a_lds[256 + tid] = atm[(size_t)b * D_TYPE + 256 + tid];
    __syncthreads();
    float acc = bf[tid];
    const float* wr = Wf + (size_t)tid * D_TYPE;
    for (int i = 0; i < D_TYPE; i++) acc = fmaf(a_lds[i], wr[i], acc);
    func_embed[b * 256 + tid] = fmaxf(acc, 0.0f);
    if (tid < 32) pad_key[((size_t)b * NP1 + 512) * 32 + tid] = endv[tid];
}

// ---------------------------------------------------------------------------
// K2b: Wcomb[k][j] = sum_i W_embed[i,k]*W_fc1[j,i]   (blocks 0..31)
//      cb[j]       = sum_i b_embed[i]*W_fc1[j,i]     (block 32)
// grid 33 x 256
// ---------------------------------------------------------------------------
__global__ __launch_bounds__(256) void comb_kernel(
    const float* __restrict__ Wemb, const float* __restrict__ bemb,
    const float* __restrict__ Wfc1, float* __restrict__ Wcomb, float* __restrict__ cbv)
{
    __shared__ float col[D_IN];
    const int tid = threadIdx.x;
    const int k = blockIdx.x;
    if (k < 32) {
        for (int p = 0; p < 4; p++) col[p * 256 + tid] = Wemb[(size_t)(p * 256 + tid) * 32 + k];
    } else {
        for (int p = 0; p < 4; p++) col[p * 256 + tid] = bemb[p * 256 + tid];
    }
    __syncthreads();
    const float* wr = Wfc1 + (size_t)tid * D_IN;
    float acc = 0.0f;
    for (int i4 = 0; i4 < 256; i4++) {
        float4 w = *(const float4*)(wr + i4 * 4);
        acc = fmaf(col[i4*4+0], w.x, acc);
        acc = fmaf(col[i4*4+1], w.y, acc);
        acc = fmaf(col[i4*4+2], w.z, acc);
        acc = fmaf(col[i4*4+3], w.w, acc);
    }
    if (k < 32) Wcomb[k * 256 + tid] = acc;
    else        cbv[tid] = acc;
}

// ---------------------------------------------------------------------------
// K3: act_pre0[b][j] = emb0[b,:] . W_fc1[j,:] + b_fc1[j] + func_embed[b][j]
// tiled 16b x 16j per block, K chunked by 256. grid (16,16) x 256
// ---------------------------------------------------------------------------
__global__ __launch_bounds__(256) void actpre_kernel(
    const float* __restrict__ emb0, const float* __restrict__ Wfc1,
    const float* __restrict__ bfc1, const float* __restrict__ func_embed,
    float* __restrict__ act_pre)
{
    __shared__ float a_lds[16 * 260];
    __shared__ float w_lds[16 * 260];
    const int tid = threadIdx.x;
    const int jt = blockIdx.x, bt = blockIdx.y;
    const int bb = tid >> 4, jj = tid & 15;
    float acc = 0.0f;
    for (int c = 0; c < 4; c++) {
        if (c) __syncthreads();
#pragma unroll
        for (int p = 0; p < 4; p++) {
            int l4 = p * 256 + tid;
            int r = l4 >> 6, k4 = l4 & 63;
            *(float4*)&a_lds[r * 260 + k4 * 4] =
                *(const float4*)(emb0 + (size_t)(bt * 16 + r) * D_IN + c * 256 + k4 * 4);
            *(float4*)&w_lds[r * 260 + k4 * 4] =
                *(const float4*)(Wfc1 + (size_t)(jt * 16 + r) * D_IN + c * 256 + k4 * 4);
        }
        __syncthreads();
#pragma unroll 8
        for (int k4 = 0; k4 < 64; k4++) {
            float4 a = *(const float4*)&a_lds[bb * 260 + k4 * 4];
            float4 w = *(const float4*)&w_lds[jj * 260 + k4 * 4];
            acc = fmaf(a.x, w.x, acc); acc = fmaf(a.y, w.y, acc);
            acc = fmaf(a.z, w.z, acc); acc = fmaf(a.w, w.w, acc);
        }
    }
    const int b = bt * 16 + bb, j = jt * 16 + jj;
    act_pre[b * 256 + j] = acc + bfc1[j] + func_embed[b * 256 + j];
}

// ---------------------------------------------------------------------------
// K4: the 33-step recurrence, one block per batch row; weights in registers.
// Produces Hall[b,t,k] (all hidden states), ssel, and the final emb output.
// grid 256 x 256
// ---------------------------------------------------------------------------
__global__ __launch_bounds__(256) void scan_kernel(
    const float* __restrict__ act_pre_in, const float* __restrict__ pad_key,
    const int* __restrict__ sel_units,
    const float* __restrict__ Wfc2, const float* __restrict__ bfc2,
    const float* __restrict__ Wih,  const float* __restrict__ bih,
    const float* __restrict__ Whh,  const float* __restrict__ bhh,
    const float* __restrict__ Wcomb, const float* __restrict__ cbv,
    const float* __restrict__ emb0, const float* __restrict__ Wemb,
    const float* __restrict__ bemb,
    float* __restrict__ Hall, float* __restrict__ emb_out)
{
    __shared__ float ap_lds[256];
    __shared__ float red_lds[256];
    __shared__ float x_lds[32];
    __shared__ float h_lds[32];
    __shared__ float gate_lds[128];
    __shared__ float es_lds[32];
    __shared__ float ssel_lds[32];
    const int tid = threadIdx.x;
    const int b = blockIdx.x;
    const int seg = tid >> 5, j = tid & 31;

    float wfc2r[32], wcr[32];
#pragma unroll
    for (int i = 0; i < 32; i++) wfc2r[i] = Wfc2[j * 256 + seg * 32 + i];
#pragma unroll
    for (int k = 0; k < 32; k++) wcr[k] = Wcomb[k * 256 + tid];
    const float cbr = cbv[tid];
    float wihr[32], whhr[32];
    float bihr = 0.0f;
    if (tid < 128) {
#pragma unroll
        for (int k = 0; k < 32; k++) { wihr[k] = Wih[tid * 32 + k]; whhr[k] = Whh[tid * 32 + k]; }
        bihr = bih[tid] + bhh[tid];
    }
    const float bfc2r = (tid < 32) ? bfc2[tid] : 0.0f;
    ap_lds[tid] = act_pre_in[b * 256 + tid];
    if (tid < 32) h_lds[tid] = 0.0f;
    float c_reg = 0.0f, ssel_reg = 0.0f;
    const float* pk_b = pad_key + (size_t)b * NP1 * 32;
    __syncthreads();

    for (int t = 0; t < SP1; ++t) {
        // A: fc2 partials over relu(act_pre)
        float part = 0.0f;
#pragma unroll
        for (int i = 0; i < 32; i++)
            part = fmaf(fmaxf(ap_lds[seg * 32 + i], 0.0f), wfc2r[i], part);
        red_lds[tid] = part;
        __syncthreads();
        if (tid < 32) {
            float x = bfc2r;
#pragma unroll
            for (int s = 0; s < 8; s++) x += red_lds[s * 32 + tid];
            x_lds[tid] = x;
        }
        __syncthreads();
        // B: LSTM gates
        if (tid < 128) {
            float g = bihr;
#pragma unroll
            for (int k = 0; k < 32; k++) g = fmaf(x_lds[k], wihr[k], g);
#pragma unroll
            for (int k = 0; k < 32; k++) g = fmaf(h_lds[k], whhr[k], g);
            gate_lds[tid] = g;
        }
        __syncthreads();
        // B2: cell/hidden update + teacher-forced gather
        if (tid < 32) {
            float ig = sigmoidf_(gate_lds[tid]);
            float fg = sigmoidf_(gate_lds[tid + 32]);
            float gg = tanhf(gate_lds[tid + 64]);
            float og = sigmoidf_(gate_lds[tid + 96]);
            c_reg = fg * c_reg + ig * gg;
            float hh = og * tanhf(c_reg);
            h_lds[tid] = hh;
            Hall[((size_t)b * SP1 + t) * 32 + tid] = hh;
            if (t < SS_) {
                int sel = sel_units[b * SS_ + t];
                float v = pk_b[(size_t)sel * 32 + tid] * INV_N;
                ssel_reg += v;
                es_lds[tid] = v;
            }
        }
        __syncthreads();
        // E: act_pre rank-32 update via Wcomb
        if (t < SS_) {
            float d = cbr;
#pragma unroll
            for (int k = 0; k < 32; k++) d = fmaf(es_lds[k], wcr[k], d);
            ap_lds[tid] += d;
            __syncthreads();
        }
    }

    // final emb output: emb0 + ssel @ W_embed^T + 32*b_embed
    if (tid < 32) ssel_lds[tid] = ssel_reg;
    __syncthreads();
#pragma unroll
    for (int p = 0; p < 4; p++) {
        int i = p * 256 + tid;
        float acc = emb0[(size_t)b * D_IN + i] + 32.0f * bemb[i];
        const float* wr = Wemb + (size_t)i * 32;
#pragma unroll
        for (int k4 = 0; k4 < 8; k4++) {
            float4 w = *(const float4*)(wr + k4 * 4);
            acc = fmaf(ssel_lds[k4*4+0], w.x, acc);
            acc = fmaf(ssel_lds[k4*4+1], w.y, acc);
            acc = fmaf(ssel_lds[k4*4+2], w.z, acc);
            acc = fmaf(ssel_lds[k4*4+3], w.w, acc);
        }
        emb_out[(size_t)b * D_IN + i] = acc;
    }
}

// ---------------------------------------------------------------------------
// K5: logits[b,t,n] = sum_k Hall[b,t,k]*pad_key[b,n,k] - (1-mask_t[b,n])*1e9
// mask_t reconstructed from m0 and tfirst (first step selecting n).
// grid (256,2) x 256
// ---------------------------------------------------------------------------
__global__ __launch_bounds__(256) void logits_kernel(
    const float* __restrict__ pad_key, const float* __restrict__ Hall,
    const float* __restrict__ avail, const int* __restrict__ sel_units,
    float* __restrict__ logits)
{
    __shared__ float m0_lds[NP1];
    __shared__ int tf_lds[NP1];
    const int tid = threadIdx.x;
    const int b = blockIdx.x, ny = blockIdx.y;
    for (int n = tid; n < NP1; n += 256) {
        m0_lds[n] = (n < NN_) ? avail[(size_t)b * NN_ + n] : 1.0f;
        tf_lds[n] = 1000;
    }
    __syncthreads();
    if (tid < SS_) m0_lds[sel_units[b * SS_ + tid]] = 1.0f;  // teacher forcing
    if (tid == 0) {
        for (int s = 0; s < SS_; s++) {
            int n = sel_units[b * SS_ + s];
            if (s < tf_lds[n]) tf_lds[n] = s;
        }
    }
    __syncthreads();
    const float* hp = Hall + (size_t)b * SP1 * 32;
    for (int n = ny * 256 + tid; n < NP1; n += 512) {
        const float* kp = pad_key + ((size_t)b * NP1 + n) * 32;
        float kr[32];
#pragma unroll
        for (int k4 = 0; k4 < 8; k4++) {
            float4 v = *(const float4*)(kp + k4 * 4);
            kr[k4*4] = v.x; kr[k4*4+1] = v.y; kr[k4*4+2] = v.z; kr[k4*4+3] = v.w;
        }
        const float m0v = m0_lds[n];
        const int tfv = tf_lds[n];
        for (int t = 0; t < SP1; t++) {
            float acc = 0.0f;
            const float* hr = hp + t * 32;   // uniform -> s_load, SGPR operands
#pragma unroll
            for (int k = 0; k < 32; k++) acc = fmaf(hr[k], kr[k], acc);
            float mv = (t <= tfv) ? m0v : 0.0f;
            logits[((size_t)b * SP1 + t) * NP1 + n] = acc - (1.0f - mv) * 1e9f;
        }
    }
}

extern "C" void kernel_launch(void* const* d_in, const int* in_sizes, int n_in,
                              void* d_out, int out_size, void* d_ws, size_t ws_size,
                              hipStream_t stream)
{
    (void)in_sizes; (void)n_in; (void)out_size; (void)ws_size;
    const float* embedding = (const float*)d_in[0];
    const float* atm       = (const float*)d_in[1];
    const float* avail     = (const float*)d_in[2];
    const float* ent       = (const float*)d_in[3];
    const int*   sel       = (const int*)  d_in[4];
    const float* endv      = (const float*)d_in[5];
    const float* Wk   = (const float*)d_in[6];
    const float* bk   = (const float*)d_in[7];
    const float* Wf   = (const float*)d_in[8];
    const float* bf   = (const float*)d_in[9];
    const float* Wfc1 = (const float*)d_in[10];
    const float* bfc1 = (const float*)d_in[11];
    const float* Wfc2 = (const float*)d_in[12];
    const float* bfc2 = (const float*)d_in[13];
    const float* Wemb = (const float*)d_in[14];
    const float* bemb = (const float*)d_in[15];
    const float* Wih  = (const float*)d_in[16];
    const float* bih  = (const float*)d_in[17];
    const float* Whh  = (const float*)d_in[18];
    const float* bhh  = (const float*)d_in[19];

    float* ws = (float*)d_ws;
    float* pad_key    = ws;                                   // 256*513*32
    float* func_embed = pad_key + (size_t)BB_ * NP1 * 32;     // 256*256
    float* act_pre    = func_embed + BB_ * 256;               // 256*256
    float* Wcomb      = act_pre + BB_ * 256;                  // 32*256
    float* cbv        = Wcomb + 32 * 256;                     // 256
    float* Hall       = cbv + 256;                            // 256*33*32

    float* logits  = (float*)d_out;
    float* emb_out = logits + (size_t)BB_ * SP1 * NP1;

    key_kernel<<<512, 256, 0, stream>>>(ent, Wk, bk, pad_key);
    func_end_kernel<<<BB_, 256, 0, stream>>>(atm, Wf, bf, endv, func_embed, pad_key);
    comb_kernel<<<33, 256, 0, stream>>>(Wemb, bemb, Wfc1, Wcomb, cbv);
    actpre_kernel<<<dim3(16, 16), 256, 0, stream>>>(embedding, Wfc1, bfc1, func_embed, act_pre);
    scan_kernel<<<BB_, 256, 0, stream>>>(act_pre, pad_key, sel, Wfc2, bfc2, Wih, bih,
                                         Whh, bhh, Wcomb, cbv, embedding, Wemb, bemb,
                                         Hall, emb_out);
    logits_kernel<<<dim3(BB_, 2), 256, 0, stream>>>(pad_key, Hall, avail, sel, logits);
}

// Round 2
// 395.346 us; speedup vs baseline: 1.2873x; 1.2873x over previous
//
#include <hip/hip_runtime.h>
#include <math.h>

#define BB_ 256
#define NN_ 512
#define SS_ 32
#define NP1 513
#define SP1 33
#define D_IN 1024
#define D_TYPE 259
#define INV_N (1.0f/512.0f)

typedef short s16x4 __attribute__((ext_vector_type(4)));
typedef short s16x8 __attribute__((ext_vector_type(8)));
typedef float f32x4 __attribute__((ext_vector_type(4)));

__device__ __forceinline__ float sigmoidf_(float x) { return 1.0f / (1.0f + expf(-x)); }
__device__ __forceinline__ short f2bf(float f) {
    unsigned u = __float_as_uint(f);
    unsigned r = (u + 0x7FFFu + ((u >> 16) & 1u)) >> 16;
    return (short)r;
}

// ---------------------------------------------------------------------------
// K1: pad_key = ENT[131072,256] x Wk^T[256,32] via bf16 MFMA 16x16x32.
// Block: 128 rows, 4 waves (each wave: 2 m-tiles x 2 n-tiles). B fragments
// (all of Wk) live in 64 VGPRs loaded once. A staged f32->bf16 in LDS,
// stride 72 (144 B, 16B-aligned b128 fragment reads). grid 1024 x 256.
// ---------------------------------------------------------------------------
__global__ __launch_bounds__(256) void key_kernel(
    const float* __restrict__ ent, const float* __restrict__ Wk,
    const float* __restrict__ bk, float* __restrict__ pad_key)
{
    __shared__ short a_lds[128 * 72];   // 18432 B
    const int tid = threadIdx.x;
    const int lane = tid & 63, w = tid >> 6;
    const int nl = lane & 15, q = lane >> 4;
    const size_t rowbase = (size_t)blockIdx.x * 128;

    // B fragments: bfr[s][t] = Wk[t*16+nl][s*32 + q*8 .. +8] as bf16
    s16x8 bfr[8][2];
#pragma unroll
    for (int s = 0; s < 8; s++)
#pragma unroll
        for (int t = 0; t < 2; t++) {
            const float* src = Wk + (size_t)(t * 16 + nl) * 256 + s * 32 + q * 8;
            float4 v0 = *(const float4*)(src);
            float4 v1 = *(const float4*)(src + 4);
            s16x8 bv;
            bv[0] = f2bf(v0.x); bv[1] = f2bf(v0.y); bv[2] = f2bf(v0.z); bv[3] = f2bf(v0.w);
            bv[4] = f2bf(v1.x); bv[5] = f2bf(v1.y); bv[6] = f2bf(v1.z); bv[7] = f2bf(v1.w);
            bfr[s][t] = bv;
        }

    f32x4 acc[2][2];
#pragma unroll
    for (int mt = 0; mt < 2; mt++)
#pragma unroll
        for (int t = 0; t < 2; t++) acc[mt][t] = (f32x4)0.0f;

    for (int kc = 0; kc < 4; ++kc) {
        __syncthreads();
#pragma unroll
        for (int p = 0; p < 8; p++) {
            int flat = p * 256 + tid;       // 0..2047
            int row = flat >> 4;            // 0..127
            int f4 = flat & 15;             // float4 index within 64-d chunk
            float4 v = *(const float4*)(ent + (rowbase + row) * 256 + kc * 64 + f4 * 4);
            s16x4 sv;
            sv[0] = f2bf(v.x); sv[1] = f2bf(v.y); sv[2] = f2bf(v.z); sv[3] = f2bf(v.w);
            *(s16x4*)&a_lds[row * 72 + f4 * 4] = sv;
        }
        __syncthreads();
#pragma unroll
        for (int ks = 0; ks < 2; ks++) {
            const int sg = kc * 2 + ks;
#pragma unroll
            for (int mt = 0; mt < 2; mt++) {
                s16x8 af = *(const s16x8*)&a_lds[(w * 32 + mt * 16 + nl) * 72 + ks * 32 + q * 8];
#pragma unroll
                for (int t = 0; t < 2; t++)
                    acc[mt][t] = __builtin_amdgcn_mfma_f32_16x16x32_bf16(af, bfr[sg][t], acc[mt][t], 0, 0, 0);
            }
        }
    }

    float bkv[2];
    bkv[0] = bk[nl]; bkv[1] = bk[16 + nl];
#pragma unroll
    for (int mt = 0; mt < 2; mt++)
#pragma unroll
        for (int t = 0; t < 2; t++)
#pragma unroll
            for (int r = 0; r < 4; r++) {
                int rowg = (int)rowbase + w * 32 + mt * 16 + q * 4 + r;
                int b = rowg >> 9, n = rowg & 511;
                pad_key[((size_t)b * NP1 + n) * 32 + t * 16 + nl] = acc[mt][t][r] + bkv[t];
            }
}

// ---------------------------------------------------------------------------
// K2: func_embed = relu(atm @ W_func^T + b_func); also end rows of pad_key
// ---------------------------------------------------------------------------
__global__ __launch_bounds__(256) void func_end_kernel(
    const float* __restrict__ atm, const float* __restrict__ Wf,
    const float* __restrict__ bf, const float* __restrict__ endv,
    float* __restrict__ func_embed, float* __restrict__ pad_key)
{
    __shared__ float a_lds[D_TYPE];
    const int b = blockIdx.x, tid = threadIdx.x;
    a_lds[tid] = atm[(size_t)b * D_TYPE + tid];
    if (tid < 3) a_lds[256 + tid] = atm[(size_t)b * D_TYPE + 256 + tid];
    __syncthreads();
    float acc = bf[tid];
    const float* wr = Wf + (size_t)tid * D_TYPE;
    for (int i = 0; i < D_TYPE; i++) acc = fmaf(a_lds[i], wr[i], acc);
    func_embed[b * 256 + tid] = fmaxf(acc, 0.0f);
    if (tid < 32) pad_key[((size_t)b * NP1 + 512) * 32 + tid] = endv[tid];
}

// ---------------------------------------------------------------------------
// K2b: Wcomb[k][j] = sum_i W_embed[i,k]*W_fc1[j,i]; cb[j] = b_embed . W_fc1[j,:]
// ---------------------------------------------------------------------------
__global__ __launch_bounds__(256) void comb_kernel(
    const float* __restrict__ Wemb, const float* __restrict__ bemb,
    const float* __restrict__ Wfc1, float* __restrict__ Wcomb, float* __restrict__ cbv)
{
    __shared__ float col[D_IN];
    const int tid = threadIdx.x;
    const int k = blockIdx.x;
    if (k < 32) {
        for (int p = 0; p < 4; p++) col[p * 256 + tid] = Wemb[(size_t)(p * 256 + tid) * 32 + k];
    } else {
        for (int p = 0; p < 4; p++) col[p * 256 + tid] = bemb[p * 256 + tid];
    }
    __syncthreads();
    const float* wr = Wfc1 + (size_t)tid * D_IN;
    float acc = 0.0f;
    for (int i4 = 0; i4 < 256; i4++) {
        float4 wv = *(const float4*)(wr + i4 * 4);
        acc = fmaf(col[i4*4+0], wv.x, acc);
        acc = fmaf(col[i4*4+1], wv.y, acc);
        acc = fmaf(col[i4*4+2], wv.z, acc);
        acc = fmaf(col[i4*4+3], wv.w, acc);
    }
    if (k < 32) Wcomb[k * 256 + tid] = acc;
    else        cbv[tid] = acc;
}

// ---------------------------------------------------------------------------
// K3: act_pre0[b][j] = emb0[b,:].W_fc1[j,:] + b_fc1[j] + func_embed[b][j]
// ---------------------------------------------------------------------------
__global__ __launch_bounds__(256) void actpre_kernel(
    const float* __restrict__ emb0, const float* __restrict__ Wfc1,
    const float* __restrict__ bfc1, const float* __restrict__ func_embed,
    float* __restrict__ act_pre)
{
    __shared__ float a_lds[16 * 260];
    __shared__ float w_lds[16 * 260];
    const int tid = threadIdx.x;
    const int jt = blockIdx.x, bt = blockIdx.y;
    const int bb = tid >> 4, jj = tid & 15;
    float acc = 0.0f;
    for (int c = 0; c < 4; c++) {
        if (c) __syncthreads();
#pragma unroll
        for (int p = 0; p < 4; p++) {
            int l4 = p * 256 + tid;
            int r = l4 >> 6, k4 = l4 & 63;
            *(float4*)&a_lds[r * 260 + k4 * 4] =
                *(const float4*)(emb0 + (size_t)(bt * 16 + r) * D_IN + c * 256 + k4 * 4);
            *(float4*)&w_lds[r * 260 + k4 * 4] =
                *(const float4*)(Wfc1 + (size_t)(jt * 16 + r) * D_IN + c * 256 + k4 * 4);
        }
        __syncthreads();
#pragma unroll 8
        for (int k4 = 0; k4 < 64; k4++) {
            float4 a = *(const float4*)&a_lds[bb * 260 + k4 * 4];
            float4 wv = *(const float4*)&w_lds[jj * 260 + k4 * 4];
            acc = fmaf(a.x, wv.x, acc); acc = fmaf(a.y, wv.y, acc);
            acc = fmaf(a.z, wv.z, acc); acc = fmaf(a.w, wv.w, acc);
        }
    }
    const int b = bt * 16 + bb, j = jt * 16 + jj;
    act_pre[b * 256 + j] = acc + bfc1[j] + func_embed[b * 256 + j];
}

// ---------------------------------------------------------------------------
// K4: precompute — for each b: cumES (serial 32 in lanes), then all 33 steps
// of ap_t -> x_t -> xg_t IN PARALLEL-ish (no LSTM dependency), plus emb_out.
// grid 256 x 256
// ---------------------------------------------------------------------------
__global__ __launch_bounds__(256) void precompute_kernel(
    const float* __restrict__ act_pre0, const float* __restrict__ pad_key,
    const int* __restrict__ sel,
    const float* __restrict__ Wfc2, const float* __restrict__ bfc2,
    const float* __restrict__ Wih, const float* __restrict__ bih,
    const float* __restrict__ bhh,
    const float* __restrict__ Wcomb, const float* __restrict__ cbv,
    const float* __restrict__ emb0, const float* __restrict__ Wemb,
    const float* __restrict__ bemb,
    float* __restrict__ xg, float* __restrict__ emb_out)
{
    __shared__ float cumE[SP1 * 32];
    __shared__ float r_lds[256];
    __shared__ float red[256];
    __shared__ float x_lds[32];
    __shared__ float ssel_l[32];
    const int tid = threadIdx.x;
    const int b = blockIdx.x;
    const int seg = tid >> 5, j = tid & 31;

    float wfc2r[32], wcr[32];
#pragma unroll
    for (int i4 = 0; i4 < 8; i4++) {
        float4 v = *(const float4*)(Wfc2 + (size_t)j * 256 + seg * 32 + i4 * 4);
        wfc2r[i4*4] = v.x; wfc2r[i4*4+1] = v.y; wfc2r[i4*4+2] = v.z; wfc2r[i4*4+3] = v.w;
    }
#pragma unroll
    for (int k = 0; k < 32; k++) wcr[k] = Wcomb[k * 256 + tid];
    const float cbr = cbv[tid];
    const float ap0 = act_pre0[b * 256 + tid];
    float wihr[32], bihr2 = 0.0f;
    if (tid < 128) {
#pragma unroll
        for (int k4 = 0; k4 < 8; k4++) {
            float4 v = *(const float4*)(Wih + (size_t)tid * 32 + k4 * 4);
            wihr[k4*4] = v.x; wihr[k4*4+1] = v.y; wihr[k4*4+2] = v.z; wihr[k4*4+3] = v.w;
        }
        bihr2 = bih[tid] + bhh[tid];
    }
    const float bfc2r = (tid < 32) ? bfc2[tid] : 0.0f;

    if (tid < 32) {
        float run = 0.0f;
        cumE[tid] = 0.0f;
        for (int s = 0; s < SS_; s++) {
            int sl = sel[b * SS_ + s];
            run += pad_key[((size_t)b * NP1 + sl) * 32 + tid] * INV_N;
            cumE[(s + 1) * 32 + tid] = run;
        }
        ssel_l[tid] = run;
    }
    __syncthreads();

    for (int t = 0; t < SP1; ++t) {
        float ap = ap0 + (float)t * cbr;
        const float4* ce = (const float4*)&cumE[t * 32];
#pragma unroll
        for (int k4 = 0; k4 < 8; k4++) {
            float4 e = ce[k4];
            ap = fmaf(e.x, wcr[k4*4], ap);   ap = fmaf(e.y, wcr[k4*4+1], ap);
            ap = fmaf(e.z, wcr[k4*4+2], ap); ap = fmaf(e.w, wcr[k4*4+3], ap);
        }
        r_lds[tid] = fmaxf(ap, 0.0f);
        __syncthreads();
        float part = 0.0f;
        const float4* rp = (const float4*)&r_lds[seg * 32];
#pragma unroll
        for (int i4 = 0; i4 < 8; i4++) {
            float4 rv = rp[i4];
            part = fmaf(rv.x, wfc2r[i4*4], part);   part = fmaf(rv.y, wfc2r[i4*4+1], part);
            part = fmaf(rv.z, wfc2r[i4*4+2], part); part = fmaf(rv.w, wfc2r[i4*4+3], part);
        }
        red[tid] = part;
        __syncthreads();
        if (tid < 32) {
            float x = bfc2r;
#pragma unroll
            for (int s = 0; s < 8; s++) x += red[s * 32 + tid];
            x_lds[tid] = x;
        }
        __syncthreads();
        if (tid < 128) {
            float g = bihr2;
            const float4* xp = (const float4*)x_lds;
#pragma unroll
            for (int k4 = 0; k4 < 8; k4++) {
                float4 xv = xp[k4];
                g = fmaf(xv.x, wihr[k4*4], g);   g = fmaf(xv.y, wihr[k4*4+1], g);
                g = fmaf(xv.z, wihr[k4*4+2], g); g = fmaf(xv.w, wihr[k4*4+3], g);
            }
            xg[((size_t)b * SP1 + t) * 128 + tid] = g;
        }
        __syncthreads();
    }

    // emb_out = emb0 + ssel @ Wemb^T + 32*b_embed
#pragma unroll
    for (int p = 0; p < 4; p++) {
        int i = p * 256 + tid;
        float acc = emb0[(size_t)b * D_IN + i] + 32.0f * bemb[i];
        const float* wr = Wemb + (size_t)i * 32;
#pragma unroll
        for (int k4 = 0; k4 < 8; k4++) {
            float4 wv = *(const float4*)(wr + k4 * 4);
            acc = fmaf(ssel_l[k4*4+0], wv.x, acc);
            acc = fmaf(ssel_l[k4*4+1], wv.y, acc);
            acc = fmaf(ssel_l[k4*4+2], wv.z, acc);
            acc = fmaf(ssel_l[k4*4+3], wv.w, acc);
        }
        emb_out[(size_t)b * D_IN + i] = acc;
    }
}

// ---------------------------------------------------------------------------
// K5: the true serial part — LSTM chain over 33 steps. One wave per b.
// gates = xg[t] + h.Whh; Whh in regs (2 gates/lane), xg in LDS, shfl gate swap.
// grid 256 x 64
// ---------------------------------------------------------------------------
__global__ __launch_bounds__(64) void lstm_kernel(
    const float* __restrict__ xg, const float* __restrict__ Whh,
    float* __restrict__ Hall)
{
    __shared__ float xg_l[SP1 * 128];
    __shared__ float h_l[32];
    const int tid = threadIdx.x;
    const int b = blockIdx.x;

    float whh0[32], whh1[32];
#pragma unroll
    for (int k4 = 0; k4 < 8; k4++) {
        float4 v0 = *(const float4*)(Whh + (size_t)tid * 32 + k4 * 4);
        float4 v1 = *(const float4*)(Whh + (size_t)(tid + 64) * 32 + k4 * 4);
        whh0[k4*4] = v0.x; whh0[k4*4+1] = v0.y; whh0[k4*4+2] = v0.z; whh0[k4*4+3] = v0.w;
        whh1[k4*4] = v1.x; whh1[k4*4+1] = v1.y; whh1[k4*4+2] = v1.z; whh1[k4*4+3] = v1.w;
    }
    const float4* xgp = (const float4*)(xg + (size_t)b * SP1 * 128);
    float4* xgl = (float4*)xg_l;
#pragma unroll
    for (int p = 0; p < 17; p++) {
        int idx = p * 64 + tid;
        if (idx < SP1 * 32) xgl[idx] = xgp[idx];
    }
    if (tid < 32) h_l[tid] = 0.0f;
    float c = 0.0f;
    __syncthreads();

    for (int t = 0; t < SP1; ++t) {
        float g0 = xg_l[t * 128 + tid];
        float g1 = xg_l[t * 128 + 64 + tid];
#pragma unroll
        for (int k = 0; k < 32; k++) {
            float hk = h_l[k];
            g0 = fmaf(hk, whh0[k], g0);
            g1 = fmaf(hk, whh1[k], g1);
        }
        float og0 = __shfl_xor(g0, 32);
        float og1 = __shfl_xor(g1, 32);
        __syncthreads();
        if (tid < 32) {
            float ig = sigmoidf_(g0);
            float fg = sigmoidf_(og0);
            float gg = tanhf(g1);
            float og = sigmoidf_(og1);
            c = fg * c + ig * gg;
            float hh = og * tanhf(c);
            h_l[tid] = hh;
            Hall[((size_t)b * SP1 + t) * 32 + tid] = hh;
        }
        __syncthreads();
    }
}

// ---------------------------------------------------------------------------
// K6: logits[b,t,n] = Hall[b,t,:].pad_key[b,n,:] - (1-mask_t)*1e9
// ---------------------------------------------------------------------------
__global__ __launch_bounds__(256) void logits_kernel(
    const float* __restrict__ pad_key, const float* __restrict__ Hall,
    const float* __restrict__ avail, const int* __restrict__ sel_units,
    float* __restrict__ logits)
{
    __shared__ float m0_lds[NP1];
    __shared__ int tf_lds[NP1];
    const int tid = threadIdx.x;
    const int b = blockIdx.x, ny = blockIdx.y;
    for (int n = tid; n < NP1; n += 256) {
        m0_lds[n] = (n < NN_) ? avail[(size_t)b * NN_ + n] : 1.0f;
        tf_lds[n] = 1000;
    }
    __syncthreads();
    if (tid < SS_) m0_lds[sel_units[b * SS_ + tid]] = 1.0f;
    if (tid == 0) {
        for (int s = 0; s < SS_; s++) {
            int n = sel_units[b * SS_ + s];
            if (s < tf_lds[n]) tf_lds[n] = s;
        }
    }
    __syncthreads();
    const float* hp = Hall + (size_t)b * SP1 * 32;
    for (int n = ny * 256 + tid; n < NP1; n += 512) {
        const float* kp = pad_key + ((size_t)b * NP1 + n) * 32;
        float kr[32];
#pragma unroll
        for (int k4 = 0; k4 < 8; k4++) {
            float4 v = *(const float4*)(kp + k4 * 4);
            kr[k4*4] = v.x; kr[k4*4+1] = v.y; kr[k4*4+2] = v.z; kr[k4*4+3] = v.w;
        }
        const float m0v = m0_lds[n];
        const int tfv = tf_lds[n];
        for (int t = 0; t < SP1; t++) {
            float acc = 0.0f;
            const float* hr = hp + t * 32;
#pragma unroll
            for (int k = 0; k < 32; k++) acc = fmaf(hr[k], kr[k], acc);
            float mv = (t <= tfv) ? m0v : 0.0f;
            logits[((size_t)b * SP1 + t) * NP1 + n] = acc - (1.0f - mv) * 1e9f;
        }
    }
}

extern "C" void kernel_launch(void* const* d_in, const int* in_sizes, int n_in,
                              void* d_out, int out_size, void* d_ws, size_t ws_size,
                              hipStream_t stream)
{
    (void)in_sizes; (void)n_in; (void)out_size; (void)ws_size;
    const float* embedding = (const float*)d_in[0];
    const float* atm       = (const float*)d_in[1];
    const float* avail     = (const float*)d_in[2];
    const float* ent       = (const float*)d_in[3];
    const int*   sel       = (const int*)  d_in[4];
    const float* endv      = (const float*)d_in[5];
    const float* Wk   = (const float*)d_in[6];
    const float* bk   = (const float*)d_in[7];
    const float* Wf   = (const float*)d_in[8];
    const float* bf   = (const float*)d_in[9];
    const float* Wfc1 = (const float*)d_in[10];
    const float* bfc1 = (const float*)d_in[11];
    const float* Wfc2 = (const float*)d_in[12];
    const float* bfc2 = (const float*)d_in[13];
    const float* Wemb = (const float*)d_in[14];
    const float* bemb = (const float*)d_in[15];
    const float* Wih  = (const float*)d_in[16];
    const float* bih  = (const float*)d_in[17];
    const float* Whh  = (const float*)d_in[18];
    const float* bhh  = (const float*)d_in[19];

    float* ws = (float*)d_ws;
    float* pad_key    = ws;                                   // 256*513*32 = 4202496
    float* func_embed = pad_key + (size_t)BB_ * NP1 * 32;     // 65536
    float* act_pre    = func_embed + BB_ * 256;               // 65536
    float* Wcomb      = act_pre + BB_ * 256;                  // 8192
    float* cbv        = Wcomb + 32 * 256;                     // 256
    float* Hall       = cbv + 256;                            // 256*33*32 = 270336
    float* xg         = Hall + (size_t)BB_ * SP1 * 32;        // 256*33*128 = 1081344

    float* logits  = (float*)d_out;
    float* emb_out = logits + (size_t)BB_ * SP1 * NP1;

    key_kernel<<<1024, 256, 0, stream>>>(ent, Wk, bk, pad_key);
    func_end_kernel<<<BB_, 256, 0, stream>>>(atm, Wf, bf, endv, func_embed, pad_key);
    comb_kernel<<<33, 256, 0, stream>>>(Wemb, bemb, Wfc1, Wcomb, cbv);
    actpre_kernel<<<dim3(16, 16), 256, 0, stream>>>(embedding, Wfc1, bfc1, func_embed, act_pre);
    precompute_kernel<<<BB_, 256, 0, stream>>>(act_pre, pad_key, sel, Wfc2, bfc2,
                                               Wih, bih, bhh, Wcomb, cbv,
                                               embedding, Wemb, bemb, xg, emb_out);
    lstm_kernel<<<BB_, 64, 0, stream>>>(xg, Whh, Hall);
    logits_kernel<<<dim3(BB_, 2), 256, 0, stream>>>(pad_key, Hall, avail, sel, logits);
}

// Round 3
// 360.168 us; speedup vs baseline: 1.4130x; 1.0977x over previous
//
#include <hip/hip_runtime.h>
#include <math.h>

#define BB_ 256
#define NN_ 512
#define SS_ 32
#define NP1 513
#define SP1 33
#define D_IN 1024
#define D_TYPE 259
#define INV_N (1.0f/512.0f)

typedef short s16x4 __attribute__((ext_vector_type(4)));
typedef short s16x8 __attribute__((ext_vector_type(8)));
typedef float f32x4 __attribute__((ext_vector_type(4)));

__device__ __forceinline__ float sigmoidf_(float x) { return 1.0f / (1.0f + expf(-x)); }
__device__ __forceinline__ short f2bf(float f) {
    unsigned u = __float_as_uint(f);
    unsigned r = (u + 0x7FFFu + ((u >> 16) & 1u)) >> 16;
    return (short)r;
}

// ---------------------------------------------------------------------------
// K1: pad_key[b,n,:] (n<512) = ENT[131072,256] x Wk^T via bf16 MFMA 16x16x32.
// grid 1024 x 256. ~25-30 us, HBM-bound (134 MB read + 17 MB write).
// ---------------------------------------------------------------------------
__global__ __launch_bounds__(256) void key_kernel(
    const float* __restrict__ ent, const float* __restrict__ Wk,
    const float* __restrict__ bk, float* __restrict__ pad_key)
{
    __shared__ short a_lds[128 * 72];
    const int tid = threadIdx.x;
    const int lane = tid & 63, w = tid >> 6;
    const int nl = lane & 15, q = lane >> 4;
    const size_t rowbase = (size_t)blockIdx.x * 128;

    s16x8 bfr[8][2];
#pragma unroll
    for (int s = 0; s < 8; s++)
#pragma unroll
        for (int t = 0; t < 2; t++) {
            const float* src = Wk + (size_t)(t * 16 + nl) * 256 + s * 32 + q * 8;
            float4 v0 = *(const float4*)(src);
            float4 v1 = *(const float4*)(src + 4);
            s16x8 bv;
            bv[0] = f2bf(v0.x); bv[1] = f2bf(v0.y); bv[2] = f2bf(v0.z); bv[3] = f2bf(v0.w);
            bv[4] = f2bf(v1.x); bv[5] = f2bf(v1.y); bv[6] = f2bf(v1.z); bv[7] = f2bf(v1.w);
            bfr[s][t] = bv;
        }

    f32x4 acc[2][2];
#pragma unroll
    for (int mt = 0; mt < 2; mt++)
#pragma unroll
        for (int t = 0; t < 2; t++) acc[mt][t] = (f32x4)0.0f;

    for (int kc = 0; kc < 4; ++kc) {
        __syncthreads();
#pragma unroll
        for (int p = 0; p < 8; p++) {
            int flat = p * 256 + tid;
            int row = flat >> 4;
            int f4 = flat & 15;
            float4 v = *(const float4*)(ent + (rowbase + row) * 256 + kc * 64 + f4 * 4);
            s16x4 sv;
            sv[0] = f2bf(v.x); sv[1] = f2bf(v.y); sv[2] = f2bf(v.z); sv[3] = f2bf(v.w);
            *(s16x4*)&a_lds[row * 72 + f4 * 4] = sv;
        }
        __syncthreads();
#pragma unroll
        for (int ks = 0; ks < 2; ks++) {
            const int sg = kc * 2 + ks;
#pragma unroll
            for (int mt = 0; mt < 2; mt++) {
                s16x8 af = *(const s16x8*)&a_lds[(w * 32 + mt * 16 + nl) * 72 + ks * 32 + q * 8];
#pragma unroll
                for (int t = 0; t < 2; t++)
                    acc[mt][t] = __builtin_amdgcn_mfma_f32_16x16x32_bf16(af, bfr[sg][t], acc[mt][t], 0, 0, 0);
            }
        }
    }

    float bkv[2];
    bkv[0] = bk[nl]; bkv[1] = bk[16 + nl];
#pragma unroll
    for (int mt = 0; mt < 2; mt++)
#pragma unroll
        for (int t = 0; t < 2; t++)
#pragma unroll
            for (int r = 0; r < 4; r++) {
                int rowg = (int)rowbase + w * 32 + mt * 16 + q * 4 + r;
                int b = rowg >> 9, n = rowg & 511;
                pad_key[((size_t)b * NP1 + n) * 32 + t * 16 + nl] = acc[mt][t][r] + bkv[t];
            }
}

// ---------------------------------------------------------------------------
// K2: Wcomb[k][j] = sum_i Wemb[i,k]*Wfc1[j,i]; cbv[j] = bemb . Wfc1[j,:]
// grid 33 x 256 (small; L2-served).
// ---------------------------------------------------------------------------
__global__ __launch_bounds__(256) void comb_kernel(
    const float* __restrict__ Wemb, const float* __restrict__ bemb,
    const float* __restrict__ Wfc1, float* __restrict__ Wcomb, float* __restrict__ cbv)
{
    __shared__ float col[D_IN];
    const int tid = threadIdx.x;
    const int k = blockIdx.x;
    if (k < 32) {
        for (int p = 0; p < 4; p++) col[p * 256 + tid] = Wemb[(size_t)(p * 256 + tid) * 32 + k];
    } else {
        for (int p = 0; p < 4; p++) col[p * 256 + tid] = bemb[p * 256 + tid];
    }
    __syncthreads();
    const float* wr = Wfc1 + (size_t)tid * D_IN;
    float acc = 0.0f;
    for (int i4 = 0; i4 < 256; i4++) {
        float4 wv = *(const float4*)(wr + i4 * 4);
        acc = fmaf(col[i4*4+0], wv.x, acc);
        acc = fmaf(col[i4*4+1], wv.y, acc);
        acc = fmaf(col[i4*4+2], wv.z, acc);
        acc = fmaf(col[i4*4+3], wv.w, acc);
    }
    if (k < 32) Wcomb[k * 256 + tid] = acc;
    else        cbv[tid] = acc;
}

// ---------------------------------------------------------------------------
// K3: act_pre0[b][j] = emb0[b,:].Wfc1[j,:] + bfc1[j]
//                    + relu(atm[b,:].Wf[j,:] + bf[j])    (func fused in)
// grid (16,16) x 256, all loads coalesced via LDS tiles.
// ---------------------------------------------------------------------------
__global__ __launch_bounds__(256) void actpre_kernel(
    const float* __restrict__ emb0, const float* __restrict__ Wfc1,
    const float* __restrict__ bfc1, const float* __restrict__ atm,
    const float* __restrict__ Wf, const float* __restrict__ bf,
    float* __restrict__ act_pre)
{
    __shared__ float a_lds[16 * 260];
    __shared__ float w_lds[16 * 260];
    const int tid = threadIdx.x;
    const int jt = blockIdx.x, bt = blockIdx.y;
    const int bb = tid >> 4, jj = tid & 15;

    // ---- func phase: stage atm/Wf tiles (stride 259, dword coalesced) ----
#pragma unroll 4
    for (int r = 0; r < 16; r++) {
        a_lds[r * 260 + tid] = atm[(size_t)(bt * 16 + r) * D_TYPE + tid];
        w_lds[r * 260 + tid] = Wf[(size_t)(jt * 16 + r) * D_TYPE + tid];
        if (tid < 3) {
            a_lds[r * 260 + 256 + tid] = atm[(size_t)(bt * 16 + r) * D_TYPE + 256 + tid];
            w_lds[r * 260 + 256 + tid] = Wf[(size_t)(jt * 16 + r) * D_TYPE + 256 + tid];
        }
    }
    __syncthreads();
    float accf = 0.0f;
    {
        const float4* ap = (const float4*)&a_lds[bb * 260];
        const float4* wp = (const float4*)&w_lds[jj * 260];
#pragma unroll 8
        for (int i4 = 0; i4 < 64; i4++) {
            float4 a = ap[i4]; float4 wv = wp[i4];
            accf = fmaf(a.x, wv.x, accf); accf = fmaf(a.y, wv.y, accf);
            accf = fmaf(a.z, wv.z, accf); accf = fmaf(a.w, wv.w, accf);
        }
        for (int i = 256; i < 259; i++) accf = fmaf(a_lds[bb * 260 + i], w_lds[jj * 260 + i], accf);
    }

    // ---- main phase: emb0 . Wfc1 ----
    float acc = 0.0f;
    for (int c = 0; c < 4; c++) {
        __syncthreads();
#pragma unroll
        for (int p = 0; p < 4; p++) {
            int l4 = p * 256 + tid;
            int r = l4 >> 6, k4 = l4 & 63;
            *(float4*)&a_lds[r * 260 + k4 * 4] =
                *(const float4*)(emb0 + (size_t)(bt * 16 + r) * D_IN + c * 256 + k4 * 4);
            *(float4*)&w_lds[r * 260 + k4 * 4] =
                *(const float4*)(Wfc1 + (size_t)(jt * 16 + r) * D_IN + c * 256 + k4 * 4);
        }
        __syncthreads();
#pragma unroll 8
        for (int k4 = 0; k4 < 64; k4++) {
            float4 a = *(const float4*)&a_lds[bb * 260 + k4 * 4];
            float4 wv = *(const float4*)&w_lds[jj * 260 + k4 * 4];
            acc = fmaf(a.x, wv.x, acc); acc = fmaf(a.y, wv.y, acc);
            acc = fmaf(a.z, wv.z, acc); acc = fmaf(a.w, wv.w, acc);
        }
    }
    const int b = bt * 16 + bb, j = jt * 16 + jj;
    act_pre[b * 256 + j] = acc + bfc1[j] + fmaxf(accf + bf[j], 0.0f);
}

// ---------------------------------------------------------------------------
// K4 mega: per batch row b, everything else:
//   P1 stage keys (pad 33, conflict-free) + mask/tfirst + cumE prefix
//   P2 33x (ap -> relu -> fc2 -> x -> xg) rank-32 updates, xg kept in LDS
//   P3 LSTM chain, wave 0, h via register shuffles -> h_all LDS
//   P4 logits = H[33x32] . K^T[32x513] via bf16 MFMA + mask epilogue
//   P5 emb_out
// grid 256 x 256, ~100 KB LDS (1 block/CU).
// ---------------------------------------------------------------------------
__global__ __launch_bounds__(256) void mega_kernel(
    const float* __restrict__ act_pre0, const float* __restrict__ pad_key,
    const int* __restrict__ sel,
    const float* __restrict__ Wfc2, const float* __restrict__ bfc2,
    const float* __restrict__ Wih, const float* __restrict__ bih,
    const float* __restrict__ bhh, const float* __restrict__ Whh,
    const float* __restrict__ Wcomb, const float* __restrict__ cbv,
    const float* __restrict__ emb0, const float* __restrict__ Wemb,
    const float* __restrict__ bemb, const float* __restrict__ endv,
    const float* __restrict__ avail,
    float* __restrict__ logits, float* __restrict__ emb_out)
{
    __shared__ float k_l[NP1 * 33];      // keys, padded stride 33
    __shared__ float m0_l[NP1];
    __shared__ int   tf_l[NP1];
    __shared__ float cumE[SP1 * 32];
    __shared__ float r_lds[256];
    __shared__ float red[256];
    __shared__ float x_lds[32];
    __shared__ float xg_l[SP1 * 128];
    __shared__ float h_all[SP1 * 32];
    __shared__ float ssel_l[32];

    const int tid = threadIdx.x;
    const int b = blockIdx.x;
    const int lane = tid & 63, w = tid >> 6;
    const int seg = tid >> 5, j32 = tid & 31;

    // ---- register preloads ----
    float wfc2r[32];
#pragma unroll
    for (int i4 = 0; i4 < 8; i4++) {
        float4 v = *(const float4*)(Wfc2 + (size_t)j32 * 256 + seg * 32 + i4 * 4);
        wfc2r[i4*4] = v.x; wfc2r[i4*4+1] = v.y; wfc2r[i4*4+2] = v.z; wfc2r[i4*4+3] = v.w;
    }
    float wcr[32];
#pragma unroll
    for (int k = 0; k < 32; k++) wcr[k] = Wcomb[k * 256 + tid];
    const float cbr = cbv[tid];
    const float ap0 = act_pre0[b * 256 + tid];
    float wihr[32], bihr2 = 0.0f;
    if (tid < 128) {
#pragma unroll
        for (int k4 = 0; k4 < 8; k4++) {
            float4 v = *(const float4*)(Wih + (size_t)tid * 32 + k4 * 4);
            wihr[k4*4] = v.x; wihr[k4*4+1] = v.y; wihr[k4*4+2] = v.z; wihr[k4*4+3] = v.w;
        }
        bihr2 = bih[tid] + bhh[tid];
    }
    float whh0[32], whh1[32];
    if (tid < 64) {
#pragma unroll
        for (int k4 = 0; k4 < 8; k4++) {
            float4 v0 = *(const float4*)(Whh + (size_t)tid * 32 + k4 * 4);
            float4 v1 = *(const float4*)(Whh + (size_t)(tid + 64) * 32 + k4 * 4);
            whh0[k4*4] = v0.x; whh0[k4*4+1] = v0.y; whh0[k4*4+2] = v0.z; whh0[k4*4+3] = v0.w;
            whh1[k4*4] = v1.x; whh1[k4*4+1] = v1.y; whh1[k4*4+2] = v1.z; whh1[k4*4+3] = v1.w;
        }
    }
    const float bfc2r = (tid < 32) ? bfc2[tid] : 0.0f;

    // ---- P1: stage keys + mask init ----
    {
        const float4* src = (const float4*)(pad_key + (size_t)b * NP1 * 32);
#pragma unroll
        for (int p = 0; p < 16; p++) {
            int idx = p * 256 + tid;         // 0..4095 -> n<512
            float4 v = src[idx];
            int n = idx >> 3, f4 = idx & 7;
            float* d = &k_l[n * 33 + f4 * 4];
            d[0] = v.x; d[1] = v.y; d[2] = v.z; d[3] = v.w;
        }
        if (tid < 32) k_l[512 * 33 + tid] = endv[tid];
    }
    for (int n = tid; n < NP1; n += 256) {
        m0_l[n] = (n < NN_) ? avail[(size_t)b * NN_ + n] : 1.0f;
        tf_l[n] = 1000;
    }
    __syncthreads();
    if (tid < SS_) m0_l[sel[b * SS_ + tid]] = 1.0f;   // teacher forcing
    if (tid == 0) {
        for (int s = 0; s < SS_; s++) {
            int n = sel[b * SS_ + s];
            if (s < tf_l[n]) tf_l[n] = s;
        }
    }
    if (tid < 32) {
        float run = 0.0f;
        cumE[tid] = 0.0f;
        for (int s = 0; s < SS_; s++) {
            int sl = sel[b * SS_ + s];
            run += k_l[sl * 33 + tid] * INV_N;
            cumE[(s + 1) * 32 + tid] = run;
        }
        ssel_l[tid] = run;
    }
    __syncthreads();

    // ---- P2: xg for all t ----
    for (int t = 0; t < SP1; ++t) {
        float ap = ap0 + (float)t * cbr;
        const float4* ce = (const float4*)&cumE[t * 32];
#pragma unroll
        for (int k4 = 0; k4 < 8; k4++) {
            float4 e = ce[k4];
            ap = fmaf(e.x, wcr[k4*4], ap);   ap = fmaf(e.y, wcr[k4*4+1], ap);
            ap = fmaf(e.z, wcr[k4*4+2], ap); ap = fmaf(e.w, wcr[k4*4+3], ap);
        }
        r_lds[tid] = fmaxf(ap, 0.0f);
        __syncthreads();
        float part = 0.0f;
        const float4* rp = (const float4*)&r_lds[seg * 32];
#pragma unroll
        for (int i4 = 0; i4 < 8; i4++) {
            float4 rv = rp[i4];
            part = fmaf(rv.x, wfc2r[i4*4], part);   part = fmaf(rv.y, wfc2r[i4*4+1], part);
            part = fmaf(rv.z, wfc2r[i4*4+2], part); part = fmaf(rv.w, wfc2r[i4*4+3], part);
        }
        red[tid] = part;
        __syncthreads();
        if (tid < 32) {
            float x = bfc2r;
#pragma unroll
            for (int s = 0; s < 8; s++) x += red[s * 32 + tid];
            x_lds[tid] = x;
        }
        __syncthreads();
        if (tid < 128) {
            float g = bihr2;
            const float4* xp = (const float4*)x_lds;
#pragma unroll
            for (int k4 = 0; k4 < 8; k4++) {
                float4 xv = xp[k4];
                g = fmaf(xv.x, wihr[k4*4], g);   g = fmaf(xv.y, wihr[k4*4+1], g);
                g = fmaf(xv.z, wihr[k4*4+2], g); g = fmaf(xv.w, wihr[k4*4+3], g);
            }
            xg_l[t * 128 + tid] = g;
        }
        __syncthreads();
    }

    // ---- P3: LSTM chain (wave 0, register-shuffle h) ----
    if (tid < 64) {
        float c = 0.0f, h = 0.0f;
        for (int t = 0; t < SP1; ++t) {
            float g0 = xg_l[t * 128 + tid];
            float g1 = xg_l[t * 128 + 64 + tid];
            if (t > 0) {
#pragma unroll
                for (int k = 0; k < 32; k++) {
                    float hk = __shfl(h, k);
                    g0 = fmaf(hk, whh0[k], g0);
                    g1 = fmaf(hk, whh1[k], g1);
                }
            }
            float og0 = __shfl_xor(g0, 32);
            float og1 = __shfl_xor(g1, 32);
            float ig = sigmoidf_(g0);
            float fg = sigmoidf_(og0);
            float gg = tanhf(g1);
            float og = sigmoidf_(og1);
            float cn = fg * c + ig * gg;
            float hn = og * tanhf(cn);
            if (tid < 32) {
                c = cn; h = hn;
                h_all[t * 32 + tid] = hn;
            }
        }
    }
    __syncthreads();

    // ---- P4: logits via bf16 MFMA ----
    {
        const int nl = lane & 15, q = lane >> 4;
        s16x8 afr[3];
#pragma unroll
        for (int mt = 0; mt < 3; mt++) {
            int row = mt * 16 + nl;     // t index
            s16x8 av;
#pragma unroll
            for (int jj = 0; jj < 8; jj++) {
                float v = (row < SP1) ? h_all[row * 32 + q * 8 + jj] : 0.0f;
                av[jj] = f2bf(v);
            }
            afr[mt] = av;
        }
        for (int nt = w; nt < 33; nt += 4) {
            int n = nt * 16 + nl;
            s16x8 bv;
#pragma unroll
            for (int jj = 0; jj < 8; jj++) {
                float v = (n < NP1) ? k_l[n * 33 + q * 8 + jj] : 0.0f;
                bv[jj] = f2bf(v);
            }
            f32x4 acc[3];
#pragma unroll
            for (int mt = 0; mt < 3; mt++)
                acc[mt] = __builtin_amdgcn_mfma_f32_16x16x32_bf16(afr[mt], bv, (f32x4)0.0f, 0, 0, 0);
            float m0v = (n < NP1) ? m0_l[n] : 0.0f;
            int tfv = (n < NP1) ? tf_l[n] : 0;
#pragma unroll
            for (int mt = 0; mt < 3; mt++)
#pragma unroll
                for (int r = 0; r < 4; r++) {
                    int t = mt * 16 + q * 4 + r;
                    if (t < SP1 && n < NP1) {
                        float mv = (t <= tfv) ? m0v : 0.0f;
                        logits[((size_t)b * SP1 + t) * NP1 + n] = acc[mt][r] - (1.0f - mv) * 1e9f;
                    }
                }
        }
    }

    // ---- P5: emb_out = emb0 + ssel.Wemb^T + 32*bemb ----
#pragma unroll
    for (int p = 0; p < 4; p++) {
        int i = p * 256 + tid;
        float acc = emb0[(size_t)b * D_IN + i] + 32.0f * bemb[i];
        const float* wr = Wemb + (size_t)i * 32;
#pragma unroll
        for (int k4 = 0; k4 < 8; k4++) {
            float4 wv = *(const float4*)(wr + k4 * 4);
            acc = fmaf(ssel_l[k4*4+0], wv.x, acc);
            acc = fmaf(ssel_l[k4*4+1], wv.y, acc);
            acc = fmaf(ssel_l[k4*4+2], wv.z, acc);
            acc = fmaf(ssel_l[k4*4+3], wv.w, acc);
        }
        emb_out[(size_t)b * D_IN + i] = acc;
    }
}

extern "C" void kernel_launch(void* const* d_in, const int* in_sizes, int n_in,
                              void* d_out, int out_size, void* d_ws, size_t ws_size,
                              hipStream_t stream)
{
    (void)in_sizes; (void)n_in; (void)out_size; (void)ws_size;
    const float* embedding = (const float*)d_in[0];
    const float* atm       = (const float*)d_in[1];
    const float* avail     = (const float*)d_in[2];
    const float* ent       = (const float*)d_in[3];
    const int*   sel       = (const int*)  d_in[4];
    const float* endv      = (const float*)d_in[5];
    const float* Wk   = (const float*)d_in[6];
    const float* bk   = (const float*)d_in[7];
    const float* Wf   = (const float*)d_in[8];
    const float* bf   = (const float*)d_in[9];
    const float* Wfc1 = (const float*)d_in[10];
    const float* bfc1 = (const float*)d_in[11];
    const float* Wfc2 = (const float*)d_in[12];
    const float* bfc2 = (const float*)d_in[13];
    const float* Wemb = (const float*)d_in[14];
    const float* bemb = (const float*)d_in[15];
    const float* Wih  = (const float*)d_in[16];
    const float* bih  = (const float*)d_in[17];
    const float* Whh  = (const float*)d_in[18];
    const float* bhh  = (const float*)d_in[19];

    float* ws = (float*)d_ws;
    float* pad_key = ws;                                  // 256*513*32
    float* act_pre = pad_key + (size_t)BB_ * NP1 * 32;    // 256*256
    float* Wcomb   = act_pre + BB_ * 256;                 // 32*256
    float* cbv     = Wcomb + 32 * 256;                    // 256

    float* logits  = (float*)d_out;
    float* emb_out = logits + (size_t)BB_ * SP1 * NP1;

    key_kernel<<<1024, 256, 0, stream>>>(ent, Wk, bk, pad_key);
    comb_kernel<<<33, 256, 0, stream>>>(Wemb, bemb, Wfc1, Wcomb, cbv);
    actpre_kernel<<<dim3(16, 16), 256, 0, stream>>>(embedding, Wfc1, bfc1, atm, Wf, bf, act_pre);
    mega_kernel<<<BB_, 256, 0, stream>>>(act_pre, pad_key, sel, Wfc2, bfc2,
                                         Wih, bih, bhh, Whh, Wcomb, cbv,
                                         embedding, Wemb, bemb, endv, avail,
                                         logits, emb_out);
}

// Round 4
// 318.430 us; speedup vs baseline: 1.5982x; 1.1311x over previous
//
#include <hip/hip_runtime.h>
#include <math.h>

#define BB_ 256
#define NN_ 512
#define SS_ 32
#define NP1 513
#define SP1 33
#define D_IN 1024
#define D_TYPE 259
#define INV_N (1.0f/512.0f)

typedef short s16x4 __attribute__((ext_vector_type(4)));
typedef short s16x8 __attribute__((ext_vector_type(8)));
typedef float f32x4 __attribute__((ext_vector_type(4)));

#if defined(__has_builtin)
#if __has_builtin(__builtin_amdgcn_rcpf)
#define FRCP(x) __builtin_amdgcn_rcpf(x)
#else
#define FRCP(x) (1.0f / (x))
#endif
#else
#define FRCP(x) (1.0f / (x))
#endif

__device__ __forceinline__ float fsig(float x) { return FRCP(1.0f + __expf(-x)); }
__device__ __forceinline__ float ftanh(float x) { return fmaf(-2.0f, FRCP(1.0f + __expf(2.0f * x)), 1.0f); }
__device__ __forceinline__ short f2bf(float f) {
    unsigned u = __float_as_uint(f);
    unsigned r = (u + 0x7FFFu + ((u >> 16) & 1u)) >> 16;
    return (short)r;
}

// ---------------------------------------------------------------------------
// prep: blocks 0..32  -> WcombT[j][k] = sum_i Wemb[i,k]*Wfc1[j,i]; cbv
//       blocks 33..288 -> act_pre[b][j] = emb0.Wfc1 + bfc1 + relu(atm.Wf + bf)
// ---------------------------------------------------------------------------
__global__ __launch_bounds__(256) void prep_kernel(
    const float* __restrict__ Wemb, const float* __restrict__ bemb,
    const float* __restrict__ Wfc1, const float* __restrict__ emb0,
    const float* __restrict__ bfc1, const float* __restrict__ atm,
    const float* __restrict__ Wf, const float* __restrict__ bf,
    float* __restrict__ WcombT, float* __restrict__ cbv,
    float* __restrict__ act_pre)
{
    __shared__ float col[D_IN];
    __shared__ float a_lds[16 * 260];
    __shared__ float w_lds[16 * 260];
    const int tid = threadIdx.x;

    if (blockIdx.x < 33) {
        // ---- comb body ----
        const int k = blockIdx.x;
        if (k < 32) {
            for (int p = 0; p < 4; p++) col[p * 256 + tid] = Wemb[(size_t)(p * 256 + tid) * 32 + k];
        } else {
            for (int p = 0; p < 4; p++) col[p * 256 + tid] = bemb[p * 256 + tid];
        }
        __syncthreads();
        const float* wr = Wfc1 + (size_t)tid * D_IN;
        float acc = 0.0f;
        for (int i4 = 0; i4 < 256; i4++) {
            float4 wv = *(const float4*)(wr + i4 * 4);
            acc = fmaf(col[i4*4+0], wv.x, acc);
            acc = fmaf(col[i4*4+1], wv.y, acc);
            acc = fmaf(col[i4*4+2], wv.z, acc);
            acc = fmaf(col[i4*4+3], wv.w, acc);
        }
        if (k < 32) WcombT[tid * 32 + k] = acc;   // transposed for coalesced mega read
        else        cbv[tid] = acc;
    } else {
        // ---- actpre body ----
        const int idx = blockIdx.x - 33;
        const int jt = idx & 15, bt = idx >> 4;
        const int bb = tid >> 4, jj = tid & 15;

        // func phase
#pragma unroll 4
        for (int r = 0; r < 16; r++) {
            a_lds[r * 260 + tid] = atm[(size_t)(bt * 16 + r) * D_TYPE + tid];
            w_lds[r * 260 + tid] = Wf[(size_t)(jt * 16 + r) * D_TYPE + tid];
            if (tid < 3) {
                a_lds[r * 260 + 256 + tid] = atm[(size_t)(bt * 16 + r) * D_TYPE + 256 + tid];
                w_lds[r * 260 + 256 + tid] = Wf[(size_t)(jt * 16 + r) * D_TYPE + 256 + tid];
            }
        }
        __syncthreads();
        float accf = 0.0f;
        {
            const float4* ap = (const float4*)&a_lds[bb * 260];
            const float4* wp = (const float4*)&w_lds[jj * 260];
#pragma unroll 8
            for (int i4 = 0; i4 < 64; i4++) {
                float4 a = ap[i4]; float4 wv = wp[i4];
                accf = fmaf(a.x, wv.x, accf); accf = fmaf(a.y, wv.y, accf);
                accf = fmaf(a.z, wv.z, accf); accf = fmaf(a.w, wv.w, accf);
            }
            for (int i = 256; i < 259; i++) accf = fmaf(a_lds[bb * 260 + i], w_lds[jj * 260 + i], accf);
        }
        // main phase
        float acc = 0.0f;
        for (int c = 0; c < 4; c++) {
            __syncthreads();
#pragma unroll
            for (int p = 0; p < 4; p++) {
                int l4 = p * 256 + tid;
                int r = l4 >> 6, k4 = l4 & 63;
                *(float4*)&a_lds[r * 260 + k4 * 4] =
                    *(const float4*)(emb0 + (size_t)(bt * 16 + r) * D_IN + c * 256 + k4 * 4);
                *(float4*)&w_lds[r * 260 + k4 * 4] =
                    *(const float4*)(Wfc1 + (size_t)(jt * 16 + r) * D_IN + c * 256 + k4 * 4);
            }
            __syncthreads();
#pragma unroll 8
            for (int k4 = 0; k4 < 64; k4++) {
                float4 a = *(const float4*)&a_lds[bb * 260 + k4 * 4];
                float4 wv = *(const float4*)&w_lds[jj * 260 + k4 * 4];
                acc = fmaf(a.x, wv.x, acc); acc = fmaf(a.y, wv.y, acc);
                acc = fmaf(a.z, wv.z, acc); acc = fmaf(a.w, wv.w, acc);
            }
        }
        const int b = bt * 16 + bb, j = jt * 16 + jj;
        act_pre[b * 256 + j] = acc + bfc1[j] + fmaxf(accf + bf[j], 0.0f);
    }
}

// ---------------------------------------------------------------------------
// mega: one block per b. P0 keys (MFMA, in-LDS); P1 masks/cumE (prefix scan);
// P2 phase-split xg (4 barriers); P3 LSTM (fast transcendentals);
// P4 logits MFMA; P5 emb_out.
// ---------------------------------------------------------------------------
__global__ __launch_bounds__(256, 1) void mega_kernel(
    const float* __restrict__ ent, const float* __restrict__ Wk,
    const float* __restrict__ bk, const float* __restrict__ endv,
    const float* __restrict__ act_pre0, const int* __restrict__ sel,
    const float* __restrict__ Wfc2, const float* __restrict__ bfc2,
    const float* __restrict__ Wih, const float* __restrict__ bih,
    const float* __restrict__ bhh, const float* __restrict__ Whh,
    const float* __restrict__ WcombT, const float* __restrict__ cbv,
    const float* __restrict__ emb0, const float* __restrict__ Wemb,
    const float* __restrict__ bemb, const float* __restrict__ avail,
    float* __restrict__ logits, float* __restrict__ emb_out)
{
    __shared__ float k_l[NP1 * 33];      // 67.7 KB keys, stride 33
    __shared__ float u_l[17028];         // union: a_st(P0) | rap(0..8580)+red(8580..17028) | xg(0..4224)
    __shared__ float x_l[SP1 * 32];      // also prefix-scan scratch
    __shared__ float h_all[SP1 * 32];
    __shared__ float cumE_l[SP1 * 32];
    __shared__ float m0_l[NP1];
    __shared__ int   tf_l[NP1];
    __shared__ float ssel_l[32];

    short* a_st  = (short*)u_l;
    float* rap_l = u_l;                  // stride 260
    float* red_l = u_l + 8580;           // stride 256
    float* xg_l  = u_l;                  // [t*128+g], after rap dead

    const int tid = threadIdx.x;
    const int b = blockIdx.x;
    const int lane = tid & 63, w = tid >> 6;
    const int nl = lane & 15, q = lane >> 4;

    // ================= P0: keys into k_l via bf16 MFMA =================
    {
        s16x8 bfr[8][2];
#pragma unroll
        for (int s = 0; s < 8; s++)
#pragma unroll
            for (int t = 0; t < 2; t++) {
                const float* src = Wk + (size_t)(t * 16 + nl) * 256 + s * 32 + q * 8;
                float4 v0 = *(const float4*)(src);
                float4 v1 = *(const float4*)(src + 4);
                s16x8 bv;
                bv[0] = f2bf(v0.x); bv[1] = f2bf(v0.y); bv[2] = f2bf(v0.z); bv[3] = f2bf(v0.w);
                bv[4] = f2bf(v1.x); bv[5] = f2bf(v1.y); bv[6] = f2bf(v1.z); bv[7] = f2bf(v1.w);
                bfr[s][t] = bv;
            }
        float bkv[2];
        bkv[0] = bk[nl]; bkv[1] = bk[16 + nl];
        const float* entb = ent + (size_t)b * NN_ * 256;

        for (int chunk = 0; chunk < 4; ++chunk) {
            f32x4 acc[2][2];
#pragma unroll
            for (int mt = 0; mt < 2; mt++)
#pragma unroll
                for (int t = 0; t < 2; t++) acc[mt][t] = (f32x4)0.0f;

            for (int kc = 0; kc < 4; ++kc) {
                __syncthreads();
#pragma unroll
                for (int p = 0; p < 8; p++) {
                    int flat = p * 256 + tid;
                    int row = flat >> 4;
                    int f4 = flat & 15;
                    float4 v = *(const float4*)(entb + (size_t)(chunk * 128 + row) * 256 + kc * 64 + f4 * 4);
                    s16x4 sv;
                    sv[0] = f2bf(v.x); sv[1] = f2bf(v.y); sv[2] = f2bf(v.z); sv[3] = f2bf(v.w);
                    *(s16x4*)&a_st[row * 72 + f4 * 4] = sv;
                }
                __syncthreads();
#pragma unroll
                for (int ks = 0; ks < 2; ks++) {
                    const int sg = kc * 2 + ks;
#pragma unroll
                    for (int mt = 0; mt < 2; mt++) {
                        s16x8 af = *(const s16x8*)&a_st[(w * 32 + mt * 16 + nl) * 72 + ks * 32 + q * 8];
#pragma unroll
                        for (int t = 0; t < 2; t++)
                            acc[mt][t] = __builtin_amdgcn_mfma_f32_16x16x32_bf16(af, bfr[sg][t], acc[mt][t], 0, 0, 0);
                    }
                }
            }
#pragma unroll
            for (int mt = 0; mt < 2; mt++)
#pragma unroll
                for (int t = 0; t < 2; t++)
#pragma unroll
                    for (int r = 0; r < 4; r++) {
                        int n = chunk * 128 + w * 32 + mt * 16 + q * 4 + r;
                        k_l[n * 33 + t * 16 + nl] = acc[mt][t][r] + bkv[t];
                    }
        }
        if (tid < 32) k_l[512 * 33 + tid] = endv[tid];
        for (int n = tid; n < NP1; n += 256) {
            m0_l[n] = (n < NN_) ? avail[(size_t)b * NN_ + n] : 1.0f;
            tf_l[n] = 1000;
        }
    }
    __syncthreads();

    // ================= P1: teacher-force mask, tfirst, cumE prefix ======
    {
        const int k = tid & 31, sq = tid >> 5;      // 8 groups x 32 lanes
        const int sq4 = sq * 4;
        float v0, v1, v2, v3;
        {
            int s0 = sel[b * SS_ + sq4 + 0];
            int s1 = sel[b * SS_ + sq4 + 1];
            int s2 = sel[b * SS_ + sq4 + 2];
            int s3 = sel[b * SS_ + sq4 + 3];
            v0 = k_l[s0 * 33 + k] * INV_N;
            v1 = k_l[s1 * 33 + k] * INV_N;
            v2 = k_l[s2 * 33 + k] * INV_N;
            v3 = k_l[s3 * 33 + k] * INV_N;
        }
        float p0 = v0, p1 = p0 + v1, p2 = p1 + v2, p3 = p2 + v3;
        x_l[sq * 32 + k] = p3;                       // group totals (scratch)
        if (tid < SS_) {
            int n = sel[b * SS_ + tid];
            m0_l[n] = 1.0f;
            atomicMin(&tf_l[n], tid);
        }
        __syncthreads();
        float off = 0.0f;
        for (int p = 0; p < 8; p++) if (p < sq) off += x_l[p * 32 + k];
        cumE_l[(sq4 + 1) * 32 + k] = off + p0;
        cumE_l[(sq4 + 2) * 32 + k] = off + p1;
        cumE_l[(sq4 + 3) * 32 + k] = off + p2;
        cumE_l[(sq4 + 4) * 32 + k] = off + p3;
        if (tid < 32) cumE_l[tid] = 0.0f;
        if (sq == 7) ssel_l[k] = off + p3;
    }
    __syncthreads();

    // ================= P2 Phase A: rap[t][j] for all t ==================
    {
        float wcr[32];
#pragma unroll
        for (int k4 = 0; k4 < 8; k4++) {
            float4 v = *(const float4*)(WcombT + (size_t)tid * 32 + k4 * 4);
            wcr[k4*4] = v.x; wcr[k4*4+1] = v.y; wcr[k4*4+2] = v.z; wcr[k4*4+3] = v.w;
        }
        const float cbr = cbv[tid];
        const float ap0v = act_pre0[b * 256 + tid];
        for (int t = 0; t < SP1; ++t) {
            float ap = fmaf((float)t, cbr, ap0v);
            const float4* ce = (const float4*)&cumE_l[t * 32];
#pragma unroll
            for (int k4 = 0; k4 < 8; k4++) {
                float4 e = ce[k4];
                ap = fmaf(e.x, wcr[k4*4], ap);   ap = fmaf(e.y, wcr[k4*4+1], ap);
                ap = fmaf(e.z, wcr[k4*4+2], ap); ap = fmaf(e.w, wcr[k4*4+3], ap);
            }
            rap_l[t * 260 + tid] = fmaxf(ap, 0.0f);
        }
    }
    __syncthreads();

    // ================= P2 Phase B: fc2 partials ========================
    {
        const int seg = tid >> 5, i = tid & 31;
        float wfc2r[32];
#pragma unroll
        for (int i4 = 0; i4 < 8; i4++) {
            float4 v = *(const float4*)(Wfc2 + (size_t)i * 256 + seg * 32 + i4 * 4);
            wfc2r[i4*4] = v.x; wfc2r[i4*4+1] = v.y; wfc2r[i4*4+2] = v.z; wfc2r[i4*4+3] = v.w;
        }
        for (int t = 0; t < SP1; ++t) {
            float part = 0.0f;
            const float4* rp = (const float4*)&rap_l[t * 260 + seg * 32];
#pragma unroll
            for (int i4 = 0; i4 < 8; i4++) {
                float4 rv = rp[i4];
                part = fmaf(rv.x, wfc2r[i4*4], part);   part = fmaf(rv.y, wfc2r[i4*4+1], part);
                part = fmaf(rv.z, wfc2r[i4*4+2], part); part = fmaf(rv.w, wfc2r[i4*4+3], part);
            }
            red_l[t * 256 + seg * 32 + i] = part;
        }
    }
    __syncthreads();

    // ================= P2 Phase C: reduce -> x_l =======================
    for (int p = 0; p < 5; p++) {
        int idx = p * 256 + tid;
        if (idx < SP1 * 32) {
            int t = idx >> 5, i = idx & 31;
            float x = bfc2[i];
#pragma unroll
            for (int s = 0; s < 8; s++) x += red_l[t * 256 + s * 32 + i];
            x_l[t * 32 + i] = x;
        }
    }
    __syncthreads();

    // ================= P2 Phase D: gates pre-h -> xg_l =================
    {
        const int g = tid & 127, half = tid >> 7;
        float wihr[32];
#pragma unroll
        for (int k4 = 0; k4 < 8; k4++) {
            float4 v = *(const float4*)(Wih + (size_t)g * 32 + k4 * 4);
            wihr[k4*4] = v.x; wihr[k4*4+1] = v.y; wihr[k4*4+2] = v.z; wihr[k4*4+3] = v.w;
        }
        const float bihg = bih[g] + bhh[g];
        for (int t = half; t < SP1; t += 2) {
            float gg = bihg;
            const float4* xp = (const float4*)&x_l[t * 32];
#pragma unroll
            for (int k4 = 0; k4 < 8; k4++) {
                float4 xv = xp[k4];
                gg = fmaf(xv.x, wihr[k4*4], gg);   gg = fmaf(xv.y, wihr[k4*4+1], gg);
                gg = fmaf(xv.z, wihr[k4*4+2], gg); gg = fmaf(xv.w, wihr[k4*4+3], gg);
            }
            xg_l[t * 128 + g] = gg;
        }
    }
    __syncthreads();

    // ================= P3: LSTM chain (wave 0) =========================
    if (tid < 64) {
        float whh0[32], whh1[32];
#pragma unroll
        for (int k4 = 0; k4 < 8; k4++) {
            float4 v0 = *(const float4*)(Whh + (size_t)tid * 32 + k4 * 4);
            float4 v1 = *(const float4*)(Whh + (size_t)(tid + 64) * 32 + k4 * 4);
            whh0[k4*4] = v0.x; whh0[k4*4+1] = v0.y; whh0[k4*4+2] = v0.z; whh0[k4*4+3] = v0.w;
            whh1[k4*4] = v1.x; whh1[k4*4+1] = v1.y; whh1[k4*4+2] = v1.z; whh1[k4*4+3] = v1.w;
        }
        float c = 0.0f, h = 0.0f;
        for (int t = 0; t < SP1; ++t) {
            float g0 = xg_l[t * 128 + tid];
            float g1 = xg_l[t * 128 + 64 + tid];
            if (t > 0) {
#pragma unroll
                for (int k = 0; k < 32; k++) {
                    float hk = __shfl(h, k);
                    g0 = fmaf(hk, whh0[k], g0);
                    g1 = fmaf(hk, whh1[k], g1);
                }
            }
            float og0 = __shfl_xor(g0, 32);
            float og1 = __shfl_xor(g1, 32);
            float ig = fsig(g0);
            float fg = fsig(og0);
            float gv = ftanh(g1);
            float og = fsig(og1);
            float cn = fg * c + ig * gv;
            float hn = og * ftanh(cn);
            if (tid < 32) {
                c = cn; h = hn;
                h_all[t * 32 + tid] = hn;
            }
        }
    }
    __syncthreads();

    // ================= P4: logits via bf16 MFMA ========================
    {
        s16x8 afr[3];
#pragma unroll
        for (int mt = 0; mt < 3; mt++) {
            int row = mt * 16 + nl;
            s16x8 av;
#pragma unroll
            for (int jj = 0; jj < 8; jj++) {
                float v = (row < SP1) ? h_all[row * 32 + q * 8 + jj] : 0.0f;
                av[jj] = f2bf(v);
            }
            afr[mt] = av;
        }
        for (int nt = w; nt < 33; nt += 4) {
            int n = nt * 16 + nl;
            s16x8 bv;
#pragma unroll
            for (int jj = 0; jj < 8; jj++) {
                float v = (n < NP1) ? k_l[n * 33 + q * 8 + jj] : 0.0f;
                bv[jj] = f2bf(v);
            }
            f32x4 acc[3];
#pragma unroll
            for (int mt = 0; mt < 3; mt++)
                acc[mt] = __builtin_amdgcn_mfma_f32_16x16x32_bf16(afr[mt], bv, (f32x4)0.0f, 0, 0, 0);
            float m0v = (n < NP1) ? m0_l[n] : 0.0f;
            int tfv = (n < NP1) ? tf_l[n] : 0;
#pragma unroll
            for (int mt = 0; mt < 3; mt++)
#pragma unroll
                for (int r = 0; r < 4; r++) {
                    int t = mt * 16 + q * 4 + r;
                    if (t < SP1 && n < NP1) {
                        float mv = (t <= tfv) ? m0v : 0.0f;
                        logits[((size_t)b * SP1 + t) * NP1 + n] = acc[mt][r] - (1.0f - mv) * 1e9f;
                    }
                }
        }
    }

    // ================= P5: emb_out =====================================
#pragma unroll
    for (int p = 0; p < 4; p++) {
        int i = p * 256 + tid;
        float acc = emb0[(size_t)b * D_IN + i] + 32.0f * bemb[i];
        const float* wr = Wemb + (size_t)i * 32;
#pragma unroll
        for (int k4 = 0; k4 < 8; k4++) {
            float4 wv = *(const float4*)(wr + k4 * 4);
            acc = fmaf(ssel_l[k4*4+0], wv.x, acc);
            acc = fmaf(ssel_l[k4*4+1], wv.y, acc);
            acc = fmaf(ssel_l[k4*4+2], wv.z, acc);
            acc = fmaf(ssel_l[k4*4+3], wv.w, acc);
        }
        emb_out[(size_t)b * D_IN + i] = acc;
    }
}

extern "C" void kernel_launch(void* const* d_in, const int* in_sizes, int n_in,
                              void* d_out, int out_size, void* d_ws, size_t ws_size,
                              hipStream_t stream)
{
    (void)in_sizes; (void)n_in; (void)out_size; (void)ws_size;
    const float* embedding = (const float*)d_in[0];
    const float* atm       = (const float*)d_in[1];
    const float* avail     = (const float*)d_in[2];
    const float* ent       = (const float*)d_in[3];
    const int*   sel       = (const int*)  d_in[4];
    const float* endv      = (const float*)d_in[5];
    const float* Wk   = (const float*)d_in[6];
    const float* bk   = (const float*)d_in[7];
    const float* Wf   = (const float*)d_in[8];
    const float* bf   = (const float*)d_in[9];
    const float* Wfc1 = (const float*)d_in[10];
    const float* bfc1 = (const float*)d_in[11];
    const float* Wfc2 = (const float*)d_in[12];
    const float* bfc2 = (const float*)d_in[13];
    const float* Wemb = (const float*)d_in[14];
    const float* bemb = (const float*)d_in[15];
    const float* Wih  = (const float*)d_in[16];
    const float* bih  = (const float*)d_in[17];
    const float* Whh  = (const float*)d_in[18];
    const float* bhh  = (const float*)d_in[19];

    float* ws = (float*)d_ws;
    float* act_pre = ws;                       // 256*256
    float* WcombT  = act_pre + BB_ * 256;      // 256*32
    float* cbv     = WcombT + 256 * 32;        // 256

    float* logits  = (float*)d_out;
    float* emb_out = logits + (size_t)BB_ * SP1 * NP1;

    prep_kernel<<<289, 256, 0, stream>>>(Wemb, bemb, Wfc1, embedding, bfc1,
                                         atm, Wf, bf, WcombT, cbv, act_pre);
    mega_kernel<<<BB_, 256, 0, stream>>>(ent, Wk, bk, endv, act_pre, sel,
                                         Wfc2, bfc2, Wih, bih, bhh, Whh,
                                         WcombT, cbv, embedding, Wemb, bemb,
                                         avail, logits, emb_out);
}